// Round 1
// 323.496 us; speedup vs baseline: 1.0430x; 1.0430x over previous
//
#include <hip/hip_runtime.h>
#include <stdint.h>

// ---------------------------------------------------------------------------
// SelfAttention: LN -> QKV (bf16 MFMA GEMM) -> S=QK^T/32 -> softmax -> att*V
// B=4, N=2048, D=H=1024. Outputs: att fp32 [4,2048,2048] ++ out fp32 [4,2048,1024]
// R5: k_qkv (fused N=3072) and k_scores moved to the 256^2 8-phase template:
//     BK=64, 512 thr (8 waves 2x4), 128 KB LDS dbuf, counted vmcnt(4) at
//     phases 4/8 only (loads stay in flight across raw s_barrier), setprio
//     around MFMA clusters, XCD-bijective block swizzle. k_out stays on the
//     proven 128^2 body this round.
// Staging-liveness proof (per 4-phase K-tile group, hold-all-frags variant):
//   reads of a tile's LDS happen only at its phases 1,2  =>  buffer fully
//   dead after P2. Stage map P1:(t+1)B0 P2:(t+1)B1 P3:(t+2)A0 P4:(t+2)A1
//   P5:(t+2)B0 P6:(t+2)B1 P7:(t+3)A0 P8:(t+3)A1 -- every write issues >=1
//   barrier after the slot's last read; vmcnt(4)+barrier at P4/P8 lands the
//   next tile before its P1/P5 reads. Overflow tiles clamp to NT-2 (dead buf).
// ---------------------------------------------------------------------------

typedef __attribute__((ext_vector_type(8))) short short8;   // 8 bf16 (4 VGPRs)
typedef __attribute__((ext_vector_type(4))) float floatx4;  // MFMA acc
typedef __attribute__((ext_vector_type(4))) uint16_t u16x4;

__device__ __forceinline__ uint16_t f2bf(float f) {
    union { float f; uint32_t u; } v; v.f = f;
    uint32_t r = v.u + 0x7fffu + ((v.u >> 16) & 1u);  // RNE
    return (uint16_t)(r >> 16);
}

// async global->LDS, 16B per lane. LDS dest is wave-uniform base + lane*16.
typedef const uint32_t __attribute__((address_space(1)))* gas1_t;
typedef uint32_t __attribute__((address_space(3)))* las3_t;
__device__ __forceinline__ void gload_lds16(const uint16_t* g, uint16_t* l) {
    __builtin_amdgcn_global_load_lds((gas1_t)g, (las3_t)l, 16, 0, 0);
}

__device__ __forceinline__ void s_bar()  { asm volatile("s_barrier" ::: "memory"); }
__device__ __forceinline__ void lgkm0()  { asm volatile("s_waitcnt lgkmcnt(0)" ::: "memory"); }
template<int N> __device__ __forceinline__ void vmw() {
    asm volatile("s_waitcnt vmcnt(%0)" :: "n"(N) : "memory");
}

// ---------------------------------------------------------------------------
// 256x256 8-phase GEMM: C = A * Bt^T. A:[M,K], Bt:[N,K] bf16 row-major.
// 512 threads = 8 waves (2M x 4N), per-wave 128x64 output, BK=64.
// LDS 128 KB: buf b at b*32768 elems; A at +0 (16384 elems), B at +16384.
// 16B-seg XOR swizzle (phys_seg = seg ^ (row&7)): staged via pre-swizzled
// global source + linear LDS dest; readers XOR the same way. 0 bank conflicts
// (proven in the R4 128^2 kernel).
// EPI 0: fp32 store * alpha (ldc).  EPI 1: fused-qkv bf16 store + bias, the
//        3072-wide output de-interleaves into q|k|v planes of 8192x1024.
// ---------------------------------------------------------------------------
template<int EPI>
__device__ __forceinline__ void gemm256(
    const uint16_t* __restrict__ A, const uint16_t* __restrict__ Bt,
    const int K, const int NT, const int m0, const int n0,
    float* __restrict__ Cf, uint16_t* __restrict__ Cb, const int ldc,
    const float* __restrict__ bq, const float* __restrict__ bk,
    const float* __restrict__ bv, const float alpha)
{
    __shared__ uint16_t sm[65536];  // 128 KB

    const int t = threadIdx.x;

    // ---- staging geometry: thread t covers row (t>>3), 16B-seg (t&7) ----
    const int srow = t >> 3;                  // 0..63
    const int sseg = (t & 7) ^ (srow & 7);    // pre-swizzled global seg
    const uint16_t* gA = A + (size_t)(m0 + srow) * K + sseg * 8;
    const uint16_t* gB = Bt + (size_t)(n0 + srow) * K + sseg * 8;
    uint16_t* ldst = sm + t * 8;              // linear LDS dest (lane*16B)

    // stage(kt, h): h 0=A.half0 1=A.half1 2=B.half0 3=B.half1 (half=128 rows)
    auto STAGE = [&](int kt, int h) {
        kt = (kt < NT) ? kt : (NT - 2);       // overflow -> dead even buffer
        const uint16_t* g = (h & 2) ? gB : gA;
        const size_t roff = (size_t)(h & 1) * 128 * K + (size_t)kt * 64;
        uint16_t* d = ldst + (kt & 1) * 32768 + (h & 2) * 8192 + (h & 1) * 8192;
        gload_lds16(g + roff, d);
        gload_lds16(g + roff + (size_t)64 * K, d + 4096);
    };

    // ---- reader geometry ----
    const int lane = t & 63;
    const int wid  = t >> 6;
    const int wm   = wid >> 2;        // 0..1  (M half of tile)
    const int wn   = wid & 3;         // 0..3  (N quarter)
    const int quad = lane >> 4;
    const int lrow = lane & 15;
    const int swz  = lrow & 7;
    const int ksg0 = (quad ^ swz) * 8;
    const int ksg1 = ((4 + quad) ^ swz) * 8;
    const int aoff = (wm * 128 + lrow) * 64;
    const int boff = (wn * 64 + lrow) * 64;

    const uint16_t* lA0 = sm;
    const uint16_t* lB0 = sm + 16384;
    const uint16_t* lA1 = sm + 32768;
    const uint16_t* lB1 = sm + 49152;

#define RDA(P, mi, ks) (*(const short8*)((P) + aoff + (mi) * 1024 + ((ks) ? ksg1 : ksg0)))
#define RDB(P, ni, ks) (*(const short8*)((P) + boff + (ni) * 1024 + ((ks) ? ksg1 : ksg0)))

    floatx4 acc[8][4];
#pragma unroll
    for (int mi = 0; mi < 8; ++mi)
#pragma unroll
        for (int ni = 0; ni < 4; ++ni)
            acc[mi][ni] = floatx4{0.f, 0.f, 0.f, 0.f};

    short8 Af[8][2], Bf[4][2];

#define READ_A(P, MI0)                                   \
    _Pragma("unroll")                                    \
    for (int mi = 0; mi < 4; ++mi) {                     \
        Af[MI0 + mi][0] = RDA(P, MI0 + mi, 0);           \
        Af[MI0 + mi][1] = RDA(P, MI0 + mi, 1);           \
    }
#define READ_B(P, NI0)                                   \
    _Pragma("unroll")                                    \
    for (int ni = 0; ni < 2; ++ni) {                     \
        Bf[NI0 + ni][0] = RDB(P, NI0 + ni, 0);           \
        Bf[NI0 + ni][1] = RDB(P, NI0 + ni, 1);           \
    }
#define MFMA_Q(MI0, NI0)                                                     \
    __builtin_amdgcn_s_setprio(1);                                           \
    _Pragma("unroll")                                                        \
    for (int mi = MI0; mi < MI0 + 4; ++mi)                                   \
        _Pragma("unroll")                                                    \
        for (int ni = NI0; ni < NI0 + 2; ++ni)                               \
            _Pragma("unroll")                                                \
            for (int ks = 0; ks < 2; ++ks)                                   \
                acc[mi][ni] = __builtin_amdgcn_mfma_f32_16x16x32_bf16(       \
                    Af[mi][ks], Bf[ni][ks], acc[mi][ni], 0, 0, 0);           \
    __builtin_amdgcn_s_setprio(0);

    // ---- prologue: tile0 complete + tile1 A halves; 2 halves stay in flight
    STAGE(0, 0); STAGE(0, 1); STAGE(0, 2); STAGE(0, 3);
    STAGE(1, 0); STAGE(1, 1);
    vmw<4>();
    s_bar();

    const int NI = NT >> 1;
    for (int it = 0; it < NI; ++it) {
        const int te = it * 2;  // even tile -> buf0; te+1 -> buf1

        // ================= tile te (buf0) =================
        // P1: read A[0-3],B[0-1]; compute (mi0-3 x ni0-1)
        READ_A(lA0, 0); READ_B(lB0, 0);
        STAGE(te + 1, 2);
        s_bar(); lgkm0();
        MFMA_Q(0, 0);
        s_bar();
        // P2: read A[4-7],B[2-3]; compute (mi4-7 x ni2-3)
        READ_A(lA0, 4); READ_B(lB0, 2);
        STAGE(te + 1, 3);
        s_bar(); lgkm0();
        MFMA_Q(4, 2);
        s_bar();
        // P3: compute (mi0-3 x ni2-3) from held regs
        STAGE(te + 2, 0);
        s_bar();
        MFMA_Q(0, 2);
        s_bar();
        // P4: compute (mi4-7 x ni0-1); land tile te+1 before P5
        STAGE(te + 2, 1);
        s_bar();
        MFMA_Q(4, 0);
        vmw<4>();
        s_bar();

        // ================= tile te+1 (buf1) =================
        // P5
        READ_A(lA1, 0); READ_B(lB1, 0);
        STAGE(te + 2, 2);
        s_bar(); lgkm0();
        MFMA_Q(0, 0);
        s_bar();
        // P6
        READ_A(lA1, 4); READ_B(lB1, 2);
        STAGE(te + 2, 3);
        s_bar(); lgkm0();
        MFMA_Q(4, 2);
        s_bar();
        // P7
        STAGE(te + 3, 0);
        s_bar();
        MFMA_Q(0, 2);
        s_bar();
        // P8
        STAGE(te + 3, 1);
        s_bar();
        MFMA_Q(4, 0);
        vmw<4>();
        s_bar();
    }

    vmw<0>();  // drain clamped overflow stages before leaving

    // ---- epilogue: C/D layout col=lane&15, row=quad*4+reg [m89/m91] ----
    const int rbase = m0 + wm * 128 + quad * 4;
    const int cbase = n0 + wn * 64 + lrow;

    if (EPI == 1) {
        float bc[4];
        const float* bias[3] = {bq, bk, bv};
#pragma unroll
        for (int ni = 0; ni < 4; ++ni) {
            const int col = cbase + ni * 16;
            bc[ni] = bias[col >> 10][col & 1023];
        }
#pragma unroll
        for (int mi = 0; mi < 8; ++mi) {
#pragma unroll
            for (int ni = 0; ni < 4; ++ni) {
                const int row = rbase + mi * 16;
                const int col = cbase + ni * 16;
                const int z = col >> 10, h = col & 1023;
#pragma unroll
                for (int r = 0; r < 4; ++r)
                    Cb[(size_t)z * 8388608 + (size_t)(row + r) * 1024 + h] =
                        f2bf(acc[mi][ni][r] + bc[ni]);
            }
        }
    } else {
#pragma unroll
        for (int mi = 0; mi < 8; ++mi) {
#pragma unroll
            for (int ni = 0; ni < 4; ++ni) {
                const int row = rbase + mi * 16;
                const int col = cbase + ni * 16;
#pragma unroll
                for (int r = 0; r < 4; ++r)
                    Cf[(size_t)(row + r) * ldc + col] = acc[mi][ni][r] * alpha;
            }
        }
    }
#undef RDA
#undef RDB
#undef READ_A
#undef READ_B
#undef MFMA_Q
}

// q|k|v = xn @ [wq|wk|wv]^T + bias, fused as one GEMM M=8192 N=3072 K=1024.
__global__ __launch_bounds__(512, 2) void k_qkv(
    const uint16_t* __restrict__ xn, const uint16_t* __restrict__ wt,
    const float* __restrict__ bq, const float* __restrict__ bk,
    const float* __restrict__ bv, uint16_t* __restrict__ qkv)
{
    // grid (12, 32) = 384 blocks; bijective XCD swizzle (384 % 8 == 0)
    const int flat = blockIdx.y * 12 + blockIdx.x;
    const int s = (flat & 7) * 48 + (flat >> 3);
    const int bx = s % 12, by = s / 12;
    gemm256<1>(xn, wt, 1024, 16, by * 256, bx * 256,
               nullptr, qkv, 0, bq, bk, bv, 0.f);
}

// S = q @ k^T * (1/32), fp32 into d_out att region
__global__ __launch_bounds__(512, 2) void k_scores(
    const uint16_t* __restrict__ q, const uint16_t* __restrict__ k,
    float* __restrict__ S)
{
    // grid (8, 8, 4) = 256 blocks = 1/CU; swizzle groups same-z/y per XCD
    const int flat = blockIdx.z * 64 + blockIdx.y * 8 + blockIdx.x;
    const int s = (flat & 7) * 32 + (flat >> 3);
    const int z = s >> 6, y = (s >> 3) & 7, x = s & 7;
    gemm256<0>(q + (size_t)z * 2048 * 1024, k + (size_t)z * 2048 * 1024,
               1024, 16, y * 256, x * 256,
               S + (size_t)z * 2048 * 2048, nullptr, 2048,
               nullptr, nullptr, nullptr, 0.03125f);
}

// ---------------------------------------------------------------------------
// 128x128 BK=64 body (R4, proven) -- still used by k_out this round.
// ---------------------------------------------------------------------------
#define BM 128
#define BN 128
#define BK2 64

template<int EPI>
__device__ __forceinline__ void gemm_bt_body(
    const uint16_t* __restrict__ A, const uint16_t* __restrict__ Bt, int K,
    float* __restrict__ Cf, uint16_t* __restrict__ Cb, int ldc,
    const float* __restrict__ bias, float alpha)
{
    __shared__ uint16_t lA[BM * BK2];
    __shared__ uint16_t lB[BN * BK2];

    const int t  = threadIdx.x;
    const int m0 = blockIdx.y * BM;
    const int n0 = blockIdx.x * BN;

    const int srow = t >> 3;
    const int sseg = (t & 7) ^ (srow & 7);
    const uint16_t* ga = A + (size_t)(m0 + srow) * K + sseg * 8;
    const uint16_t* gb = Bt + (size_t)(n0 + srow) * K + sseg * 8;
    uint16_t* la = &lA[t * 8];
    uint16_t* lb = &lB[t * 8];
    const size_t rstep = (size_t)32 * K;

    const int lane = t & 63;
    const int w    = t >> 6;
    const int quad = lane >> 4;
    const int lrow = lane & 15;
    const int wm   = (w & 1) * 64;
    const int wn   = (w >> 1) * 64;
    const int swz  = lrow & 7;

    floatx4 acc[4][4];
#pragma unroll
    for (int i = 0; i < 4; i++)
#pragma unroll
        for (int j = 0; j < 4; j++)
            acc[i][j] = floatx4{0.f, 0.f, 0.f, 0.f};

    for (int k0 = 0; k0 < K; k0 += BK2) {
        __syncthreads();
        gload_lds16(ga + k0,             la);
        gload_lds16(ga + rstep + k0,     la + 2048);
        gload_lds16(ga + 2 * rstep + k0, la + 4096);
        gload_lds16(ga + 3 * rstep + k0, la + 6144);
        gload_lds16(gb + k0,             lb);
        gload_lds16(gb + rstep + k0,     lb + 2048);
        gload_lds16(gb + 2 * rstep + k0, lb + 4096);
        gload_lds16(gb + 3 * rstep + k0, lb + 6144);
        __syncthreads();

#pragma unroll
        for (int ks = 0; ks < 2; ks++) {
            short8 af[4], bf[4];
#pragma unroll
            for (int mi = 0; mi < 4; mi++)
                af[mi] = *(const short8*)&lA[(wm + mi * 16 + lrow) * BK2 +
                                             (((ks * 4 + quad) ^ swz) * 8)];
#pragma unroll
            for (int ni = 0; ni < 4; ni++)
                bf[ni] = *(const short8*)&lB[(wn + ni * 16 + lrow) * BK2 +
                                             (((ks * 4 + quad) ^ swz) * 8)];
#pragma unroll
            for (int mi = 0; mi < 4; mi++)
#pragma unroll
                for (int ni = 0; ni < 4; ni++)
                    acc[mi][ni] = __builtin_amdgcn_mfma_f32_16x16x32_bf16(
                        af[mi], bf[ni], acc[mi][ni], 0, 0, 0);
        }
    }

#pragma unroll
    for (int mi = 0; mi < 4; mi++) {
#pragma unroll
        for (int ni = 0; ni < 4; ni++) {
            const int row = m0 + wm + mi * 16 + quad * 4;
            const int col = n0 + wn + ni * 16 + lrow;
#pragma unroll
            for (int r = 0; r < 4; r++) {
                const float v = acc[mi][ni][r];
                if (EPI == 0) {
                    Cf[(size_t)(row + r) * ldc + col] = v * alpha;
                } else if (EPI == 1) {
                    Cb[(size_t)(row + r) * ldc + col] = f2bf(v + bias[col]);
                } else {
                    Cf[(size_t)(row + r) * ldc + col] = v;
                }
            }
        }
    }
}

// out = att_bf16 @ vt^T, fp32
__global__ __launch_bounds__(256) void k_out(
    const uint16_t* __restrict__ attb, const uint16_t* __restrict__ vt,
    float* __restrict__ out)
{
    const int z = blockIdx.z;
    gemm_bt_body<2>(attb + (size_t)z * 2048 * 2048, vt + (size_t)z * 1024 * 2048, 2048,
                    out + (size_t)z * 2048 * 1024, nullptr, 1024, nullptr, 0.f);
}

// ---------------------------------------------------------------------------
// LayerNorm rows of x[8192][1024] -> bf16 xn
// ---------------------------------------------------------------------------
__global__ __launch_bounds__(256) void k_ln(
    const float* __restrict__ x, const float* __restrict__ lw,
    const float* __restrict__ lb, uint16_t* __restrict__ xn)
{
    const int row = blockIdx.x;
    const int t = threadIdx.x;
    const float* xr = x + (size_t)row * 1024;
    const float4 xv = ((const float4*)xr)[t];
    float s  = xv.x + xv.y + xv.z + xv.w;
    float s2 = xv.x * xv.x + xv.y * xv.y + xv.z * xv.z + xv.w * xv.w;
#pragma unroll
    for (int off = 32; off > 0; off >>= 1) {
        s  += __shfl_xor(s, off);
        s2 += __shfl_xor(s2, off);
    }
    __shared__ float ps[4], ps2[4];
    const int w = t >> 6, lane = t & 63;
    if (lane == 0) { ps[w] = s; ps2[w] = s2; }
    __syncthreads();
    s  = ps[0] + ps[1] + ps[2] + ps[3];
    s2 = ps2[0] + ps2[1] + ps2[2] + ps2[3];
    const float mu  = s * (1.f / 1024.f);
    const float var = s2 * (1.f / 1024.f) - mu * mu;
    const float rs  = rsqrtf(var + 1e-5f);
    const float4 wv = ((const float4*)lw)[t];
    const float4 bv = ((const float4*)lb)[t];
    u16x4 o;
    o.x = f2bf((xv.x - mu) * rs * wv.x + bv.x);
    o.y = f2bf((xv.y - mu) * rs * wv.y + bv.y);
    o.z = f2bf((xv.z - mu) * rs * wv.z + bv.z);
    o.w = f2bf((xv.w - mu) * rs * wv.w + bv.w);
    ((u16x4*)(xn + (size_t)row * 1024))[t] = o;
}

// ---------------------------------------------------------------------------
// Transpose + cast weights: w[1024][1024] fp32 -> wt[1024][1024] bf16 (wt[h][d])
// ---------------------------------------------------------------------------
__global__ void k_wt(const float* __restrict__ wq, const float* __restrict__ wk,
                     const float* __restrict__ wv, uint16_t* __restrict__ wt)
{
    __shared__ float tile[32][33];
    const int z = blockIdx.z;
    const float* W = (z == 0) ? wq : ((z == 1) ? wk : wv);
    uint16_t* T = wt + (size_t)z * 1024 * 1024;
    const int c0 = blockIdx.x * 32, r0 = blockIdx.y * 32;
    const int tx = threadIdx.x, ty = threadIdx.y;  // (32,8)
#pragma unroll
    for (int i = 0; i < 4; i++)
        tile[ty + 8 * i][tx] = W[(size_t)(r0 + ty + 8 * i) * 1024 + c0 + tx];
    __syncthreads();
#pragma unroll
    for (int i = 0; i < 4; i++)
        T[(size_t)(c0 + ty + 8 * i) * 1024 + r0 + tx] = f2bf(tile[tx][ty + 8 * i]);
}

// ---------------------------------------------------------------------------
// Transpose v bf16 [2048][1024] -> vt [1024][2048] per batch.
// ---------------------------------------------------------------------------
__global__ __launch_bounds__(256) void k_vt(
    const uint16_t* __restrict__ v, uint16_t* __restrict__ vt)
{
    __shared__ uint16_t tile[64][68];
    const int b = blockIdx.z;
    const uint16_t* V = v + (size_t)b * 2048 * 1024;
    uint16_t* T = vt + (size_t)b * 1024 * 2048;
    const int h0 = blockIdx.x * 64, t0 = blockIdx.y * 64;
    const int t = threadIdx.x;
    const int rr = t >> 4;
    const int cc = (t & 15) * 4;
#pragma unroll
    for (int i = 0; i < 4; i++) {
        const int tok = rr + 16 * i;
        *(u16x4*)&tile[tok][cc] =
            *(const u16x4*)&V[(size_t)(t0 + tok) * 1024 + h0 + cc];
    }
    __syncthreads();
#pragma unroll
    for (int i = 0; i < 4; i++) {
        const int h = rr + 16 * i;
        u16x4 o;
        o.x = tile[cc + 0][h];
        o.y = tile[cc + 1][h];
        o.z = tile[cc + 2][h];
        o.w = tile[cc + 3][h];
        *(u16x4*)&T[(size_t)(h0 + h) * 2048 + t0 + cc] = o;
    }
}

// ---------------------------------------------------------------------------
// Row softmax over S[8192][2048] fp32 (in place) + bf16 copy for the PV GEMM
// ---------------------------------------------------------------------------
__global__ __launch_bounds__(256) void k_softmax(
    float* __restrict__ S, uint16_t* __restrict__ attb)
{
    const size_t row = blockIdx.x;
    float* p = S + row * 2048;
    const int t = threadIdx.x;
    float4 a = ((float4*)p)[2 * t];
    float4 b = ((float4*)p)[2 * t + 1];
    float m = fmaxf(fmaxf(fmaxf(a.x, a.y), fmaxf(a.z, a.w)),
                    fmaxf(fmaxf(b.x, b.y), fmaxf(b.z, b.w)));
#pragma unroll
    for (int off = 32; off > 0; off >>= 1) m = fmaxf(m, __shfl_xor(m, off));
    __shared__ float pm[4], pl[4];
    const int w = t >> 6, lane = t & 63;
    if (lane == 0) pm[w] = m;
    __syncthreads();
    m = fmaxf(fmaxf(pm[0], pm[1]), fmaxf(pm[2], pm[3]));

    a.x = __expf(a.x - m); a.y = __expf(a.y - m);
    a.z = __expf(a.z - m); a.w = __expf(a.w - m);
    b.x = __expf(b.x - m); b.y = __expf(b.y - m);
    b.z = __expf(b.z - m); b.w = __expf(b.w - m);
    float s = a.x + a.y + a.z + a.w + b.x + b.y + b.z + b.w;
#pragma unroll
    for (int off = 32; off > 0; off >>= 1) s += __shfl_xor(s, off);
    if (lane == 0) pl[w] = s;
    __syncthreads();
    s = pl[0] + pl[1] + pl[2] + pl[3];
    const float inv = 1.f / s;

    a.x *= inv; a.y *= inv; a.z *= inv; a.w *= inv;
    b.x *= inv; b.y *= inv; b.z *= inv; b.w *= inv;
    ((float4*)p)[2 * t]     = a;
    ((float4*)p)[2 * t + 1] = b;

    uint16_t* q = attb + row * 2048 + t * 8;
    u16x4 o0, o1;
    o0.x = f2bf(a.x); o0.y = f2bf(a.y); o0.z = f2bf(a.z); o0.w = f2bf(a.w);
    o1.x = f2bf(b.x); o1.y = f2bf(b.y); o1.z = f2bf(b.z); o1.w = f2bf(b.w);
    ((u16x4*)q)[0] = o0;
    ((u16x4*)q)[1] = o1;
}

// ---------------------------------------------------------------------------
extern "C" void kernel_launch(void* const* d_in, const int* in_sizes, int n_in,
                              void* d_out, int out_size, void* d_ws, size_t ws_size,
                              hipStream_t stream)
{
    const float* x  = (const float*)d_in[0];
    const float* wq = (const float*)d_in[1];
    const float* bq = (const float*)d_in[2];
    const float* wk = (const float*)d_in[3];
    const float* bk = (const float*)d_in[4];
    const float* wv = (const float*)d_in[5];
    const float* bv = (const float*)d_in[6];
    const float* lw = (const float*)d_in[7];
    const float* lb = (const float*)d_in[8];

    float* att = (float*)d_out;                         // [4][2048][2048] = 64 MB
    float* out = (float*)d_out + (size_t)16777216;      // [4][2048][1024] = 32 MB

    // Scratch inside d_out's att region (dead until k_scores writes all of it):
    uint16_t* xn = (uint16_t*)d_out;                    // 8,388,608 elems (16.8 MB)
    uint16_t* wt = (uint16_t*)d_out + (size_t)8388608;  // 3,145,728 elems (6.3 MB)

    // ws layout (uint16 elems), exactly q+k+v = 25,165,824 elems = 50,331,648 B:
    uint16_t* ws   = (uint16_t*)d_ws;
    uint16_t* q    = ws;
    uint16_t* k    = ws + (size_t)8388608;
    uint16_t* v    = ws + (size_t)2 * 8388608;
    uint16_t* vt   = ws;                                // overlays dead q
    uint16_t* attb = ws + (size_t)8388608;              // overlays dead k+v
    uint16_t* qkv  = q;

    if (ws_size < (size_t)50331648) return;  // OOB guard: fail clean, not crash

    k_ln<<<8192, 256, 0, stream>>>(x, lw, lb, xn);
    k_wt<<<dim3(32, 32, 3), dim3(32, 8), 0, stream>>>(wq, wk, wv, wt);
    k_qkv<<<dim3(12, 32), 512, 0, stream>>>(xn, wt, bq, bk, bv, qkv);
    k_scores<<<dim3(8, 8, 4), 512, 0, stream>>>(q, k, att);     // frees q,k
    k_vt<<<dim3(16, 32, 4), 256, 0, stream>>>(v, vt);           // vt over dead q
    k_softmax<<<8192, 256, 0, stream>>>(att, attb);             // attb over dead k+v
    k_out<<<dim3(8, 16, 4), 256, 0, stream>>>(attb, vt, out);
}

// Round 2
// 314.736 us; speedup vs baseline: 1.0720x; 1.0278x over previous
//
#include <hip/hip_runtime.h>
#include <stdint.h>

// ---------------------------------------------------------------------------
// SelfAttention: LN -> QKV (bf16 MFMA GEMM) -> S=QK^T/32 -> softmax -> att*V
// B=4, N=2048, D=H=1024. Outputs: att fp32 [4,2048,2048] ++ out fp32 [4,2048,1024]
// R6: one generalized 8-phase-family GEMM body gemm8p<BN,EPI>:
//   - BN=192 k_qkv  (grid 512 = 2 uniform rounds, kills the 384/256=75% quant tax)
//   - BN=256 k_scores (grid 256 = 1/CU)
//   - BN=128 k_out   (grid 256 = 1/CU, 3-buffer LDS rotation, K=2048)
//   Cluster order reuses Af regs (peak frags 96->64..88); whole-next-tile stage
//   burst in the last phase (WAR-safe after the preceding barrier; full-tile
//   issue->wait cover); vmcnt(OPS) counted, never 0 in loop; clamped overflow
//   stages land in an 8KB LDS trash region.
// ---------------------------------------------------------------------------

typedef __attribute__((ext_vector_type(8))) short short8;   // 8 bf16 (4 VGPRs)
typedef __attribute__((ext_vector_type(4))) float floatx4;  // MFMA acc
typedef __attribute__((ext_vector_type(4))) uint16_t u16x4;

__device__ __forceinline__ uint16_t f2bf(float f) {
    union { float f; uint32_t u; } v; v.f = f;
    uint32_t r = v.u + 0x7fffu + ((v.u >> 16) & 1u);  // RNE
    return (uint16_t)(r >> 16);
}

// async global->LDS, 16B per lane. LDS dest is wave-uniform base + lane*16.
typedef const uint32_t __attribute__((address_space(1)))* gas1_t;
typedef uint32_t __attribute__((address_space(3)))* las3_t;
__device__ __forceinline__ void gload_lds16(const uint16_t* g, uint16_t* l) {
    __builtin_amdgcn_global_load_lds((gas1_t)g, (las3_t)l, 16, 0, 0);
}

__device__ __forceinline__ void s_bar()  { asm volatile("s_barrier" ::: "memory"); }
__device__ __forceinline__ void lgkm0()  { asm volatile("s_waitcnt lgkmcnt(0)" ::: "memory"); }
template<int N> __device__ __forceinline__ void vmw() {
    asm volatile("s_waitcnt vmcnt(%0)" :: "n"(N) : "memory");
}

// ---------------------------------------------------------------------------
// gemm8p<BN,EPI>: C = A * Bt^T. A:[M,K] bf16 rm, Bt:[N,K] bf16 rm. BM=256.
// 512 thr = 8 waves (2M x 4N); per-wave 128 x (BN/4). BK=64.
// LDS: NBUF x (A 16384 + B BN*64) elems + 4096 trash. NBUF=3 for BN=128 else 2.
// 16B-seg XOR swizzle: staging thread t covers row t>>3, fetches global seg
// (t&7)^(row&7) into phys slot (t&7); readers XOR the same -> 0 bank conflicts
// (proven R4/R5). Phases per K-tile: BN=256:4, 192:3, 128:2; each phase
// { ds_reads | stage ; s_barrier ; lgkmcnt(0) ; setprio(1) 16 MFMA setprio(0) ;
//   s_barrier }, last phase stage-bursts the next-same-buffer tile and does
// the counted vmcnt(OPS) wait.
// EPI 0: fp32 store * alpha.  EPI 1: fused-qkv bf16 + bias, 3072-wide cols
//        de-interleave into q|k|v planes of 8192x1024.
// ---------------------------------------------------------------------------

#define RA(MF, MI)                                                        \
    { Af[(MF)][0] = *(const short8*)(LA + aoff + (MI) * 1024 + ksg0);     \
      Af[(MF)][1] = *(const short8*)(LA + aoff + (MI) * 1024 + ksg1); }
#define RB(NI)                                                            \
    { Bf[(NI)][0] = *(const short8*)(LB + boff + (NI) * 1024 + ksg0);     \
      Bf[(NI)][1] = *(const short8*)(LB + boff + (NI) * 1024 + ksg1); }
#define CLUST(MA, MF, NI0)                                                \
    __builtin_amdgcn_s_setprio(1);                                        \
    _Pragma("unroll") for (int mi = 0; mi < 4; ++mi)                      \
    _Pragma("unroll") for (int nn = 0; nn < 2; ++nn)                      \
    _Pragma("unroll") for (int ks = 0; ks < 2; ++ks)                      \
        acc[(MA) + mi][(NI0) + nn] =                                      \
            __builtin_amdgcn_mfma_f32_16x16x32_bf16(                      \
                Af[(MF) + mi][ks], Bf[(NI0) + nn][ks],                    \
                acc[(MA) + mi][(NI0) + nn], 0, 0, 0);                     \
    __builtin_amdgcn_s_setprio(0);
#define CLUST1(NI)                                                        \
    __builtin_amdgcn_s_setprio(1);                                        \
    _Pragma("unroll") for (int mi = 0; mi < 8; ++mi)                      \
    _Pragma("unroll") for (int ks = 0; ks < 2; ++ks)                      \
        acc[mi][(NI)] = __builtin_amdgcn_mfma_f32_16x16x32_bf16(          \
            Af[mi][ks], Bf[(NI)][ks], acc[mi][(NI)], 0, 0, 0);            \
    __builtin_amdgcn_s_setprio(0);

template<int BN, int EPI>
__device__ __forceinline__ void gemm8p(
    const uint16_t* __restrict__ A, const uint16_t* __restrict__ Bt,
    const int K, const int NT, const int m0, const int n0,
    float* __restrict__ Cf, uint16_t* __restrict__ Cb, const int ldc,
    const float* __restrict__ bq, const float* __restrict__ bk,
    const float* __restrict__ bv, const float alpha)
{
    constexpr int ABUF  = 256 * 64;            // 16384 elems
    constexpr int BP    = BN / 64;             // B stage passes (4,3,2)
    constexpr int BBUF  = BN * 64;
    constexpr int BUFSZ = ABUF + BBUF;
    constexpr int NIW   = BN / 64;             // ni frags per wave (4,3,2)
    constexpr int OPS   = 4 + BP;              // stage ops per K-tile
    constexpr int NBUF  = (BN == 128) ? 3 : 2;
    __shared__ uint16_t sm[NBUF * BUFSZ + 4096];
    uint16_t* const trash = sm + NBUF * BUFSZ;

    const int t = threadIdx.x;

    // ---- staging geometry ----
    const int srow = t >> 3;                  // 0..63
    const int sseg = (t & 7) ^ (srow & 7);    // pre-swizzled global 16B-seg
    const uint16_t* gA = A + (size_t)(m0 + srow) * K + sseg * 8;
    const uint16_t* gB = Bt + (size_t)(n0 + srow) * K + sseg * 8;

    // stage one whole K-tile (OPS async gloads); kt>=NT -> trash (never read)
    auto STGALL = [&](int kt, int bi) {
        const int live = kt < NT;
        const size_t ko = (size_t)(live ? kt : 0) * 64;
        uint16_t* const db = sm + bi * BUFSZ + t * 8;
        uint16_t* const tr = trash + t * 8;
#pragma unroll
        for (int p = 0; p < 4; ++p)
            gload_lds16(gA + (size_t)(p * 64) * K + ko,
                        live ? (db + p * 4096) : tr);
#pragma unroll
        for (int p = 0; p < BP; ++p)
            gload_lds16(gB + (size_t)(p * 64) * K + ko,
                        live ? (db + ABUF + p * 4096) : tr);
    };

    // ---- reader geometry ----
    const int lane = t & 63;
    const int wid  = t >> 6;
    const int wm   = wid >> 2;        // 0..1  (M half)
    const int wn   = wid & 3;         // 0..3  (N quarter)
    const int quad = lane >> 4;
    const int lrow = lane & 15;
    const int swz  = lrow & 7;
    const int ksg0 = (quad ^ swz) * 8;
    const int ksg1 = ((4 + quad) ^ swz) * 8;
    const int aoff = (wm * 128 + lrow) * 64;
    const int boff = (wn * (16 * NIW) + lrow) * 64;

    floatx4 acc[8][NIW];
#pragma unroll
    for (int mi = 0; mi < 8; ++mi)
#pragma unroll
        for (int ni = 0; ni < NIW; ++ni)
            acc[mi][ni] = floatx4{0.f, 0.f, 0.f, 0.f};

    short8 Af[(BN == 192) ? 8 : 4][2];
    short8 Bf[NIW][2];

    // ---- prologue: tiles 0,1 fully staged; wait tile0, keep tile1 in flight
    STGALL(0, 0);
    STGALL(1, 1);
    vmw<OPS>();
    s_bar();

    int bcur = 0, bstage = 2;  // BN==128 3-buffer rotation only
    for (int te = 0; te < NT; ++te) {
        const int bi = (BN == 128) ? bcur : (te & 1);
        const uint16_t* LA = sm + bi * BUFSZ;
        const uint16_t* LB = LA + ABUF;

        if constexpr (BN == 256) {
            // P1: Af<-lower half, Bf[0-1]; C(0..3 x 0,1)
            RA(0, 0) RA(1, 1) RA(2, 2) RA(3, 3) RB(0) RB(1)
            s_bar(); lgkm0();
            CLUST(0, 0, 0)
            s_bar();
            // P2: Bf[2-3]; C(0..3 x 2,3)
            RB(2) RB(3)
            s_bar(); lgkm0();
            CLUST(0, 0, 2)
            s_bar();
            // P3: Af<-upper half (reg reuse); C(4..7 x 0,1)
            RA(0, 4) RA(1, 5) RA(2, 6) RA(3, 7)
            s_bar(); lgkm0();
            CLUST(4, 0, 0)
            s_bar();
            // P4: burst-stage tile te+2 (this buffer: all reads done at P3's
            // lgkm0, sealed by P3's trailing barrier); C(4..7 x 2,3); wait te+1
            STGALL(te + 2, bi);
            s_bar();
            CLUST(4, 0, 2)
            vmw<OPS>();
            s_bar();
        } else if constexpr (BN == 192) {
            // P1: Af[0-3], Bf[0-1]; C(0..3 x 0,1)
            RA(0, 0) RA(1, 1) RA(2, 2) RA(3, 3) RB(0) RB(1)
            s_bar(); lgkm0();
            CLUST(0, 0, 0)
            s_bar();
            // P2: Af[4-7], Bf[2]; C(4..7 x 0,1)
            RA(4, 4) RA(5, 5) RA(6, 6) RA(7, 7) RB(2)
            s_bar(); lgkm0();
            CLUST(4, 4, 0)
            s_bar();
            // P3: burst-stage te+2; C(0..7 x 2); wait te+1
            STGALL(te + 2, bi);
            s_bar();
            CLUST1(2)
            vmw<OPS>();
            s_bar();
        } else {  // BN == 128, 3-buffer rotation
            // P1: stage te+2 into the free third buffer; Af[0-3], Bf[0-1]
            STGALL(te + 2, bstage);
            RA(0, 0) RA(1, 1) RA(2, 2) RA(3, 3) RB(0) RB(1)
            s_bar(); lgkm0();
            CLUST(0, 0, 0)
            s_bar();
            // P2: Af<-upper (reg reuse); C(4..7 x 0,1); wait te+1
            RA(0, 4) RA(1, 5) RA(2, 6) RA(3, 7)
            s_bar(); lgkm0();
            CLUST(4, 0, 0)
            vmw<OPS>();
            s_bar();
            bcur   = (bcur == 2) ? 0 : bcur + 1;
            bstage = (bstage == 2) ? 0 : bstage + 1;
        }
    }

    vmw<0>();  // drain clamped trash stages

    // ---- epilogue: C/D layout col=lane&15, row=quad*4+reg [m89/m91] ----
    const int rbase = m0 + wm * 128 + quad * 4;
    const int cbase = n0 + wn * (16 * NIW) + lrow;

    if constexpr (EPI == 1) {
        float bc[NIW];
#pragma unroll
        for (int ni = 0; ni < NIW; ++ni) {
            const int col = cbase + ni * 16;
            const int z = col >> 10;
            const float* bp = (z == 0) ? bq : ((z == 1) ? bk : bv);
            bc[ni] = bp[col & 1023];
        }
#pragma unroll
        for (int mi = 0; mi < 8; ++mi) {
#pragma unroll
            for (int ni = 0; ni < NIW; ++ni) {
                const int row = rbase + mi * 16;
                const int col = cbase + ni * 16;
                const int z = col >> 10, h = col & 1023;
#pragma unroll
                for (int r = 0; r < 4; ++r)
                    Cb[(size_t)z * 8388608 + (size_t)(row + r) * 1024 + h] =
                        f2bf(acc[mi][ni][r] + bc[ni]);
            }
        }
    } else {
#pragma unroll
        for (int mi = 0; mi < 8; ++mi) {
#pragma unroll
            for (int ni = 0; ni < NIW; ++ni) {
                const int row = rbase + mi * 16;
                const int col = cbase + ni * 16;
#pragma unroll
                for (int r = 0; r < 4; ++r)
                    Cf[(size_t)(row + r) * ldc + col] = acc[mi][ni][r] * alpha;
            }
        }
    }
}

// q|k|v = xn @ [wq|wk|wv]^T + bias, one GEMM M=8192 N=3072 K=1024, BN=192.
__global__ __launch_bounds__(512, 2) void k_qkv(
    const uint16_t* __restrict__ xn, const uint16_t* __restrict__ wt,
    const float* __restrict__ bq, const float* __restrict__ bk,
    const float* __restrict__ bv, uint16_t* __restrict__ qkv)
{
    // grid (16, 32) = 512 blocks -> 2 uniform rounds; bijective XCD swizzle
    const int flat = blockIdx.y * 16 + blockIdx.x;
    const int s = (flat & 7) * 64 + (flat >> 3);
    const int bx = s & 15, by = s >> 4;
    gemm8p<192, 1>(xn, wt, 1024, 16, by * 256, bx * 192,
                   nullptr, qkv, 0, bq, bk, bv, 0.f);
}

// S = q @ k^T * (1/32), fp32 into d_out att region. BN=256, grid 256 = 1/CU.
__global__ __launch_bounds__(512, 2) void k_scores(
    const uint16_t* __restrict__ q, const uint16_t* __restrict__ k,
    float* __restrict__ S)
{
    const int flat = blockIdx.z * 64 + blockIdx.y * 8 + blockIdx.x;
    const int s = (flat & 7) * 32 + (flat >> 3);
    const int z = s >> 6, y = (s >> 3) & 7, x = s & 7;
    gemm8p<256, 0>(q + (size_t)z * 2048 * 1024, k + (size_t)z * 2048 * 1024,
                   1024, 16, y * 256, x * 256,
                   S + (size_t)z * 2048 * 2048, nullptr, 2048,
                   nullptr, nullptr, nullptr, 0.03125f);
}

// out = att_bf16 @ vt^T, fp32. BN=128, K=2048, grid 256 = 1/CU, 3-buf LDS.
__global__ __launch_bounds__(512, 2) void k_out(
    const uint16_t* __restrict__ attb, const uint16_t* __restrict__ vt,
    float* __restrict__ out)
{
    const int flat = blockIdx.z * 64 + blockIdx.y * 8 + blockIdx.x;
    const int s = (flat & 7) * 32 + (flat >> 3);
    const int z = s >> 6, y = (s >> 3) & 7, x = s & 7;
    gemm8p<128, 0>(attb + (size_t)z * 2048 * 2048, vt + (size_t)z * 1024 * 2048,
                   2048, 32, y * 256, x * 128,
                   out + (size_t)z * 2048 * 1024, nullptr, 1024,
                   nullptr, nullptr, nullptr, 1.0f);
}

// ---------------------------------------------------------------------------
// LayerNorm rows of x[8192][1024] -> bf16 xn
// ---------------------------------------------------------------------------
__global__ __launch_bounds__(256) void k_ln(
    const float* __restrict__ x, const float* __restrict__ lw,
    const float* __restrict__ lb, uint16_t* __restrict__ xn)
{
    const int row = blockIdx.x;
    const int t = threadIdx.x;
    const float* xr = x + (size_t)row * 1024;
    const float4 xv = ((const float4*)xr)[t];
    float s  = xv.x + xv.y + xv.z + xv.w;
    float s2 = xv.x * xv.x + xv.y * xv.y + xv.z * xv.z + xv.w * xv.w;
#pragma unroll
    for (int off = 32; off > 0; off >>= 1) {
        s  += __shfl_xor(s, off);
        s2 += __shfl_xor(s2, off);
    }
    __shared__ float ps[4], ps2[4];
    const int w = t >> 6, lane = t & 63;
    if (lane == 0) { ps[w] = s; ps2[w] = s2; }
    __syncthreads();
    s  = ps[0] + ps[1] + ps[2] + ps[3];
    s2 = ps2[0] + ps2[1] + ps2[2] + ps2[3];
    const float mu  = s * (1.f / 1024.f);
    const float var = s2 * (1.f / 1024.f) - mu * mu;
    const float rs  = rsqrtf(var + 1e-5f);
    const float4 wv = ((const float4*)lw)[t];
    const float4 bv = ((const float4*)lb)[t];
    u16x4 o;
    o.x = f2bf((xv.x - mu) * rs * wv.x + bv.x);
    o.y = f2bf((xv.y - mu) * rs * wv.y + bv.y);
    o.z = f2bf((xv.z - mu) * rs * wv.z + bv.z);
    o.w = f2bf((xv.w - mu) * rs * wv.w + bv.w);
    ((u16x4*)(xn + (size_t)row * 1024))[t] = o;
}

// ---------------------------------------------------------------------------
// Transpose + cast weights: w[1024][1024] fp32 -> wt[1024][1024] bf16 (wt[h][d])
// ---------------------------------------------------------------------------
__global__ void k_wt(const float* __restrict__ wq, const float* __restrict__ wk,
                     const float* __restrict__ wv, uint16_t* __restrict__ wt)
{
    __shared__ float tile[32][33];
    const int z = blockIdx.z;
    const float* W = (z == 0) ? wq : ((z == 1) ? wk : wv);
    uint16_t* T = wt + (size_t)z * 1024 * 1024;
    const int c0 = blockIdx.x * 32, r0 = blockIdx.y * 32;
    const int tx = threadIdx.x, ty = threadIdx.y;  // (32,8)
#pragma unroll
    for (int i = 0; i < 4; i++)
        tile[ty + 8 * i][tx] = W[(size_t)(r0 + ty + 8 * i) * 1024 + c0 + tx];
    __syncthreads();
#pragma unroll
    for (int i = 0; i < 4; i++)
        T[(size_t)(c0 + ty + 8 * i) * 1024 + r0 + tx] = f2bf(tile[tx][ty + 8 * i]);
}

// ---------------------------------------------------------------------------
// Transpose v bf16 [2048][1024] -> vt [1024][2048] per batch.
// ---------------------------------------------------------------------------
__global__ __launch_bounds__(256) void k_vt(
    const uint16_t* __restrict__ v, uint16_t* __restrict__ vt)
{
    __shared__ uint16_t tile[64][68];
    const int b = blockIdx.z;
    const uint16_t* V = v + (size_t)b * 2048 * 1024;
    uint16_t* T = vt + (size_t)b * 1024 * 2048;
    const int h0 = blockIdx.x * 64, t0 = blockIdx.y * 64;
    const int t = threadIdx.x;
    const int rr = t >> 4;
    const int cc = (t & 15) * 4;
#pragma unroll
    for (int i = 0; i < 4; i++) {
        const int tok = rr + 16 * i;
        *(u16x4*)&tile[tok][cc] =
            *(const u16x4*)&V[(size_t)(t0 + tok) * 1024 + h0 + cc];
    }
    __syncthreads();
#pragma unroll
    for (int i = 0; i < 4; i++) {
        const int h = rr + 16 * i;
        u16x4 o;
        o.x = tile[cc + 0][h];
        o.y = tile[cc + 1][h];
        o.z = tile[cc + 2][h];
        o.w = tile[cc + 3][h];
        *(u16x4*)&T[(size_t)(h0 + h) * 2048 + t0 + cc] = o;
    }
}

// ---------------------------------------------------------------------------
// Row softmax over S[8192][2048] fp32 (in place) + bf16 copy for the PV GEMM
// ---------------------------------------------------------------------------
__global__ __launch_bounds__(256) void k_softmax(
    float* __restrict__ S, uint16_t* __restrict__ attb)
{
    const size_t row = blockIdx.x;
    float* p = S + row * 2048;
    const int t = threadIdx.x;
    float4 a = ((float4*)p)[2 * t];
    float4 b = ((float4*)p)[2 * t + 1];
    float m = fmaxf(fmaxf(fmaxf(a.x, a.y), fmaxf(a.z, a.w)),
                    fmaxf(fmaxf(b.x, b.y), fmaxf(b.z, b.w)));
#pragma unroll
    for (int off = 32; off > 0; off >>= 1) m = fmaxf(m, __shfl_xor(m, off));
    __shared__ float pm[4], pl[4];
    const int w = t >> 6, lane = t & 63;
    if (lane == 0) pm[w] = m;
    __syncthreads();
    m = fmaxf(fmaxf(pm[0], pm[1]), fmaxf(pm[2], pm[3]));

    a.x = __expf(a.x - m); a.y = __expf(a.y - m);
    a.z = __expf(a.z - m); a.w = __expf(a.w - m);
    b.x = __expf(b.x - m); b.y = __expf(b.y - m);
    b.z = __expf(b.z - m); b.w = __expf(b.w - m);
    float s = a.x + a.y + a.z + a.w + b.x + b.y + b.z + b.w;
#pragma unroll
    for (int off = 32; off > 0; off >>= 1) s += __shfl_xor(s, off);
    if (lane == 0) pl[w] = s;
    __syncthreads();
    s = pl[0] + pl[1] + pl[2] + pl[3];
    const float inv = 1.f / s;

    a.x *= inv; a.y *= inv; a.z *= inv; a.w *= inv;
    b.x *= inv; b.y *= inv; b.z *= inv; b.w *= inv;
    ((float4*)p)[2 * t]     = a;
    ((float4*)p)[2 * t + 1] = b;

    uint16_t* q = attb + row * 2048 + t * 8;
    u16x4 o0, o1;
    o0.x = f2bf(a.x); o0.y = f2bf(a.y); o0.z = f2bf(a.z); o0.w = f2bf(a.w);
    o1.x = f2bf(b.x); o1.y = f2bf(b.y); o1.z = f2bf(b.z); o1.w = f2bf(b.w);
    ((u16x4*)q)[0] = o0;
    ((u16x4*)q)[1] = o1;
}

// ---------------------------------------------------------------------------
extern "C" void kernel_launch(void* const* d_in, const int* in_sizes, int n_in,
                              void* d_out, int out_size, void* d_ws, size_t ws_size,
                              hipStream_t stream)
{
    const float* x  = (const float*)d_in[0];
    const float* wq = (const float*)d_in[1];
    const float* bq = (const float*)d_in[2];
    const float* wk = (const float*)d_in[3];
    const float* bk = (const float*)d_in[4];
    const float* wv = (const float*)d_in[5];
    const float* bv = (const float*)d_in[6];
    const float* lw = (const float*)d_in[7];
    const float* lb = (const float*)d_in[8];

    float* att = (float*)d_out;                         // [4][2048][2048] = 64 MB
    float* out = (float*)d_out + (size_t)16777216;      // [4][2048][1024] = 32 MB

    // Scratch inside d_out's att region (dead until k_scores writes all of it):
    uint16_t* xn = (uint16_t*)d_out;                    // 8,388,608 elems (16.8 MB)
    uint16_t* wt = (uint16_t*)d_out + (size_t)8388608;  // 3,145,728 elems (6.3 MB)

    // ws layout (uint16 elems), exactly q+k+v = 25,165,824 elems = 50,331,648 B:
    uint16_t* ws   = (uint16_t*)d_ws;
    uint16_t* q    = ws;
    uint16_t* k    = ws + (size_t)8388608;
    uint16_t* v    = ws + (size_t)2 * 8388608;
    uint16_t* vt   = ws;                                // overlays dead q
    uint16_t* attb = ws + (size_t)8388608;              // overlays dead k+v
    uint16_t* qkv  = q;

    if (ws_size < (size_t)50331648) return;  // OOB guard: fail clean, not crash

    k_ln<<<8192, 256, 0, stream>>>(x, lw, lb, xn);
    k_wt<<<dim3(32, 32, 3), dim3(32, 8), 0, stream>>>(wq, wk, wv, wt);
    k_qkv<<<dim3(16, 32), 512, 0, stream>>>(xn, wt, bq, bk, bv, qkv);
    k_scores<<<dim3(8, 8, 4), 512, 0, stream>>>(q, k, att);     // frees q,k
    k_vt<<<dim3(16, 32, 4), 256, 0, stream>>>(v, vt);           // vt over dead q
    k_softmax<<<8192, 256, 0, stream>>>(att, attb);             // attb over dead k+v
    k_out<<<dim3(8, 8, 4), 512, 0, stream>>>(attb, vt, out);
}

// Round 3
// 307.313 us; speedup vs baseline: 1.0979x; 1.0242x over previous
//
#include <hip/hip_runtime.h>
#include <stdint.h>

// ---------------------------------------------------------------------------
// SelfAttention: LN -> QKV (bf16 MFMA GEMM) -> S=QK^T/32 -> softmax -> att*V
// B=4, N=2048, D=H=1024. Outputs: att fp32 [4,2048,2048] ++ out fp32 [4,2048,1024]
// R7: de-serialize LDS reads vs MFMA. R6's per-phase {reads;bar;lgkm0;MFMA;bar}
//   summed read-time + MFMA-time (measured 5100 cy/K-tile vs 1536 cy MFMA work).
//   Intra-tile barriers are unnecessary (reads-after-reads); per K-tile only:
//     - WAR: lgkm0 + s_barrier before re-staging the buffer being read
//     - RAW: counted vmcnt(OPS) + s_barrier before reading the next tile
//   All fragment ds_reads issue up-front; compiler staggers lgkmcnt per use.
//   STGALL sits between the two MFMA halves so DMA overlaps back-half MFMAs.
//   k_out: 4Mx2N wave grid (16 reads/tile vs 20) + 3-buffer rotation ->
//   1 barrier/K-tile. BN=256 reuses Af regs (VGPR cliff); BN=192 holds all.
// ---------------------------------------------------------------------------

typedef __attribute__((ext_vector_type(8))) short short8;   // 8 bf16 (4 VGPRs)
typedef __attribute__((ext_vector_type(4))) float floatx4;  // MFMA acc
typedef __attribute__((ext_vector_type(4))) uint16_t u16x4;

__device__ __forceinline__ uint16_t f2bf(float f) {
    union { float f; uint32_t u; } v; v.f = f;
    uint32_t r = v.u + 0x7fffu + ((v.u >> 16) & 1u);  // RNE
    return (uint16_t)(r >> 16);
}

// async global->LDS, 16B per lane. LDS dest is wave-uniform base + lane*16.
typedef const uint32_t __attribute__((address_space(1)))* gas1_t;
typedef uint32_t __attribute__((address_space(3)))* las3_t;
__device__ __forceinline__ void gload_lds16(const uint16_t* g, uint16_t* l) {
    __builtin_amdgcn_global_load_lds((gas1_t)g, (las3_t)l, 16, 0, 0);
}

__device__ __forceinline__ void s_bar()  { asm volatile("s_barrier" ::: "memory"); }
__device__ __forceinline__ void lgkm0()  { asm volatile("s_waitcnt lgkmcnt(0)" ::: "memory"); }
template<int N> __device__ __forceinline__ void vmw() {
    asm volatile("s_waitcnt vmcnt(%0)" :: "n"(N) : "memory");
}

// ---------------------------------------------------------------------------
// gemm_core<BN,EPI>: C = A * Bt^T. A:[M,K] bf16 rm, Bt:[N,K] bf16 rm. BM=256.
// 512 thr = 8 waves. Wave grid: BN=128 -> 4Mx2N (per-wave 64x64), else 2Mx4N
// (per-wave 128x(BN/4)). BK=64. LDS: NBUF x (A 16384 + B BN*64) elems + 4096
// trash (clamped overflow stages). NBUF=3 for BN=128 else 2.
// 16B-seg XOR swizzle: staging thread t covers row t>>3, fetches global seg
// (t&7)^(row&7) into phys slot (t&7); readers XOR the same -> 0 bank conflicts
// (proven R4-R6).
// Per K-tile: reads up-front -> MFMA half1 -> [lgkm0; s_bar; STGALL(te+2)] ->
// MFMA half2 -> vmw<OPS>; s_bar.   (BN=128: STGALL first into free 3rd buffer,
// single s_bar per tile.)
// EPI 0: fp32 store * alpha.  EPI 1: fused-qkv bf16 + bias, 3072-wide cols
//        de-interleave into q|k|v planes of 8192x1024.
// ---------------------------------------------------------------------------

#define RA(MF, MI)                                                        \
    { Af[(MF)][0] = *(const short8*)(LA + aoff + (MI) * 1024 + ksg0);     \
      Af[(MF)][1] = *(const short8*)(LA + aoff + (MI) * 1024 + ksg1); }
#define RB(NI)                                                            \
    { Bf[(NI)][0] = *(const short8*)(LB + boff + (NI) * 1024 + ksg0);     \
      Bf[(NI)][1] = *(const short8*)(LB + boff + (NI) * 1024 + ksg1); }
// 16-MFMA cluster: acc rows MA..MA+3 from frag rows MF..MF+3, ni NI0..NI0+1
#define CLUST(MA, MF, NI0)                                                \
    __builtin_amdgcn_s_setprio(1);                                        \
    _Pragma("unroll") for (int mi = 0; mi < 4; ++mi)                      \
    _Pragma("unroll") for (int nn = 0; nn < 2; ++nn)                      \
    _Pragma("unroll") for (int ks = 0; ks < 2; ++ks)                      \
        acc[(MA) + mi][(NI0) + nn] =                                      \
            __builtin_amdgcn_mfma_f32_16x16x32_bf16(                      \
                Af[(MF) + mi][ks], Bf[(NI0) + nn][ks],                    \
                acc[(MA) + mi][(NI0) + nn], 0, 0, 0);                     \
    __builtin_amdgcn_s_setprio(0);
// 16-MFMA cluster: all 8 acc/frag rows x single ni  (BN=192 only)
#define CLUST1(NI)                                                        \
    __builtin_amdgcn_s_setprio(1);                                        \
    _Pragma("unroll") for (int mi = 0; mi < 8; ++mi)                      \
    _Pragma("unroll") for (int ks = 0; ks < 2; ++ks)                      \
        acc[mi][(NI)] = __builtin_amdgcn_mfma_f32_16x16x32_bf16(          \
            Af[mi][ks], Bf[(NI)][ks], acc[mi][(NI)], 0, 0, 0);            \
    __builtin_amdgcn_s_setprio(0);

template<int BN, int EPI>
__device__ __forceinline__ void gemm_core(
    const uint16_t* __restrict__ A, const uint16_t* __restrict__ Bt,
    const int K, const int NT, const int m0, const int n0,
    float* __restrict__ Cf, uint16_t* __restrict__ Cb, const int ldc,
    const float* __restrict__ bq, const float* __restrict__ bk,
    const float* __restrict__ bv, const float alpha)
{
    constexpr int ABUF  = 256 * 64;            // 16384 elems
    constexpr int BP    = BN / 64;             // B stage passes (4,3,2)
    constexpr int BBUF  = BN * 64;
    constexpr int BUFSZ = ABUF + BBUF;
    constexpr int OPS   = 4 + BP;              // stage ops per K-tile
    constexpr int NBUF  = (BN == 128) ? 3 : 2;
    constexpr int WAVES_N = (BN == 128) ? 2 : 4;
    constexpr int MIW  = (BN == 128) ? 4 : 8;  // mi frags per wave
    constexpr int NIW  = BN / (16 * WAVES_N);  // ni frags (4,3,4)
    constexpr int NFR  = (BN == 256) ? 4 : MIW;  // live Af frag regs
    __shared__ uint16_t sm[NBUF * BUFSZ + 4096];
    uint16_t* const trash = sm + NBUF * BUFSZ;

    const int t = threadIdx.x;

    // ---- staging geometry ----
    const int srow = t >> 3;                  // 0..63
    const int sseg = (t & 7) ^ (srow & 7);    // pre-swizzled global 16B-seg
    const uint16_t* gA = A + (size_t)(m0 + srow) * K + sseg * 8;
    const uint16_t* gB = Bt + (size_t)(n0 + srow) * K + sseg * 8;

    // stage one whole K-tile (OPS async gloads); kt>=NT -> trash (never read)
    auto STGALL = [&](int kt, int bi) {
        const int live = kt < NT;
        const size_t ko = (size_t)(live ? kt : 0) * 64;
        uint16_t* const db = sm + bi * BUFSZ + t * 8;
        uint16_t* const tr = trash + t * 8;
#pragma unroll
        for (int p = 0; p < 4; ++p)
            gload_lds16(gA + (size_t)(p * 64) * K + ko,
                        live ? (db + p * 4096) : tr);
#pragma unroll
        for (int p = 0; p < BP; ++p)
            gload_lds16(gB + (size_t)(p * 64) * K + ko,
                        live ? (db + ABUF + p * 4096) : tr);
    };

    // ---- reader geometry ----
    const int lane = t & 63;
    const int wid  = t >> 6;
    const int wm   = wid / WAVES_N;
    const int wn   = wid % WAVES_N;
    const int quad = lane >> 4;
    const int lrow = lane & 15;
    const int swz  = lrow & 7;
    const int ksg0 = (quad ^ swz) * 8;
    const int ksg1 = ((4 + quad) ^ swz) * 8;
    const int aoff = (wm * (16 * MIW) + lrow) * 64;
    const int boff = (wn * (16 * NIW) + lrow) * 64;

    floatx4 acc[MIW][NIW];
#pragma unroll
    for (int mi = 0; mi < MIW; ++mi)
#pragma unroll
        for (int ni = 0; ni < NIW; ++ni)
            acc[mi][ni] = floatx4{0.f, 0.f, 0.f, 0.f};

    short8 Af[NFR][2];
    short8 Bf[NIW][2];

    // ---- prologue: tiles 0,1 fully staged; wait tile0, keep tile1 in flight
    STGALL(0, 0);
    STGALL(1, 1);
    vmw<OPS>();
    s_bar();

    int bcur = 0, bstage = 2;  // BN==128 3-buffer rotation only
    for (int te = 0; te < NT; ++te) {
        const int bi = (BN == 128) ? bcur : (te & 1);
        const uint16_t* LA = sm + bi * BUFSZ;
        const uint16_t* LB = LA + ABUF;

        if constexpr (BN == 256) {
            // reads: lower A + all B up-front; MFMA lo x all ni while LDS
            // services; upper A into the SAME Af regs (reg-WAR sequences it
            // after the lo MFMAs issue).
            RA(0, 0) RA(1, 1) RA(2, 2) RA(3, 3)
            RB(0) RB(1) RB(2) RB(3)
            CLUST(0, 0, 0) CLUST(0, 0, 2)          // 32 MFMA, lo half
            RA(0, 4) RA(1, 5) RA(2, 6) RA(3, 7)    // upper A
            lgkm0(); s_bar();                      // WAR: all reads of bi done
            STGALL(te + 2, bi);                    // DMA overlaps hi MFMAs
            CLUST(4, 0, 0) CLUST(4, 0, 2)          // 32 MFMA, hi half
            vmw<OPS>(); s_bar();                   // RAW: te+1 landed
        } else if constexpr (BN == 192) {
            RA(0, 0) RA(1, 1) RA(2, 2) RA(3, 3)
            RA(4, 4) RA(5, 5) RA(6, 6) RA(7, 7)
            RB(0) RB(1) RB(2)
            CLUST(0, 0, 0) CLUST(4, 4, 0)          // 32 MFMA, ni0-1
            lgkm0(); s_bar();
            STGALL(te + 2, bi);
            CLUST1(2)                              // 16 MFMA, ni2
            vmw<OPS>(); s_bar();
        } else {  // BN == 128, 3-buffer rotation, 1 barrier/tile
            STGALL(te + 2, bstage);                // free buffer: no WAR wait
            RA(0, 0) RA(1, 1) RA(2, 2) RA(3, 3)
            RB(0) RB(1) RB(2) RB(3)
            CLUST(0, 0, 0) CLUST(0, 0, 2)          // 32 MFMA
            lgkm0();                               // own reads of bcur done
            vmw<OPS>(); s_bar();                   // te+1 landed; all reads done
            bcur   = (bcur == 2) ? 0 : bcur + 1;
            bstage = (bstage == 2) ? 0 : bstage + 1;
        }
    }

    vmw<0>();  // drain clamped trash stages

    // ---- epilogue: C/D layout col=lane&15, row=quad*4+reg [m89/m91] ----
    const int rbase = m0 + wm * (16 * MIW) + quad * 4;
    const int cbase = n0 + wn * (16 * NIW) + lrow;

    if constexpr (EPI == 1) {
        float bc[NIW];
#pragma unroll
        for (int ni = 0; ni < NIW; ++ni) {
            const int col = cbase + ni * 16;
            const int z = col >> 10;
            const float* bp = (z == 0) ? bq : ((z == 1) ? bk : bv);
            bc[ni] = bp[col & 1023];
        }
#pragma unroll
        for (int mi = 0; mi < MIW; ++mi) {
#pragma unroll
            for (int ni = 0; ni < NIW; ++ni) {
                const int row = rbase + mi * 16;
                const int col = cbase + ni * 16;
                const int z = col >> 10, h = col & 1023;
#pragma unroll
                for (int r = 0; r < 4; ++r)
                    Cb[(size_t)z * 8388608 + (size_t)(row + r) * 1024 + h] =
                        f2bf(acc[mi][ni][r] + bc[ni]);
            }
        }
    } else {
#pragma unroll
        for (int mi = 0; mi < MIW; ++mi) {
#pragma unroll
            for (int ni = 0; ni < NIW; ++ni) {
                const int row = rbase + mi * 16;
                const int col = cbase + ni * 16;
#pragma unroll
                for (int r = 0; r < 4; ++r)
                    Cf[(size_t)(row + r) * ldc + col] = acc[mi][ni][r] * alpha;
            }
        }
    }
}

// q|k|v = xn @ [wq|wk|wv]^T + bias, one GEMM M=8192 N=3072 K=1024, BN=192.
__global__ __launch_bounds__(512, 2) void k_qkv(
    const uint16_t* __restrict__ xn, const uint16_t* __restrict__ wt,
    const float* __restrict__ bq, const float* __restrict__ bk,
    const float* __restrict__ bv, uint16_t* __restrict__ qkv)
{
    // grid (16, 32) = 512 blocks -> 2 uniform rounds; bijective XCD swizzle
    const int flat = blockIdx.y * 16 + blockIdx.x;
    const int s = (flat & 7) * 64 + (flat >> 3);
    const int bx = s & 15, by = s >> 4;
    gemm_core<192, 1>(xn, wt, 1024, 16, by * 256, bx * 192,
                      nullptr, qkv, 0, bq, bk, bv, 0.f);
}

// S = q @ k^T * (1/32), fp32 into d_out att region. BN=256, grid 256 = 1/CU.
__global__ __launch_bounds__(512, 2) void k_scores(
    const uint16_t* __restrict__ q, const uint16_t* __restrict__ k,
    float* __restrict__ S)
{
    const int flat = blockIdx.z * 64 + blockIdx.y * 8 + blockIdx.x;
    const int s = (flat & 7) * 32 + (flat >> 3);
    const int z = s >> 6, y = (s >> 3) & 7, x = s & 7;
    gemm_core<256, 0>(q + (size_t)z * 2048 * 1024, k + (size_t)z * 2048 * 1024,
                      1024, 16, y * 256, x * 256,
                      S + (size_t)z * 2048 * 2048, nullptr, 2048,
                      nullptr, nullptr, nullptr, 0.03125f);
}

// out = att_bf16 @ vt^T, fp32. BN=128, K=2048, grid 256 = 1/CU, 3-buf LDS.
__global__ __launch_bounds__(512, 2) void k_out(
    const uint16_t* __restrict__ attb, const uint16_t* __restrict__ vt,
    float* __restrict__ out)
{
    const int flat = blockIdx.z * 64 + blockIdx.y * 8 + blockIdx.x;
    const int s = (flat & 7) * 32 + (flat >> 3);
    const int z = s >> 6, y = (s >> 3) & 7, x = s & 7;
    gemm_core<128, 0>(attb + (size_t)z * 2048 * 2048, vt + (size_t)z * 1024 * 2048,
                      2048, 32, y * 256, x * 128,
                      out + (size_t)z * 2048 * 1024, nullptr, 1024,
                      nullptr, nullptr, nullptr, 1.0f);
}

// ---------------------------------------------------------------------------
// LayerNorm rows of x[8192][1024] -> bf16 xn
// ---------------------------------------------------------------------------
__global__ __launch_bounds__(256) void k_ln(
    const float* __restrict__ x, const float* __restrict__ lw,
    const float* __restrict__ lb, uint16_t* __restrict__ xn)
{
    const int row = blockIdx.x;
    const int t = threadIdx.x;
    const float* xr = x + (size_t)row * 1024;
    const float4 xv = ((const float4*)xr)[t];
    float s  = xv.x + xv.y + xv.z + xv.w;
    float s2 = xv.x * xv.x + xv.y * xv.y + xv.z * xv.z + xv.w * xv.w;
#pragma unroll
    for (int off = 32; off > 0; off >>= 1) {
        s  += __shfl_xor(s, off);
        s2 += __shfl_xor(s2, off);
    }
    __shared__ float ps[4], ps2[4];
    const int w = t >> 6, lane = t & 63;
    if (lane == 0) { ps[w] = s; ps2[w] = s2; }
    __syncthreads();
    s  = ps[0] + ps[1] + ps[2] + ps[3];
    s2 = ps2[0] + ps2[1] + ps2[2] + ps2[3];
    const float mu  = s * (1.f / 1024.f);
    const float var = s2 * (1.f / 1024.f) - mu * mu;
    const float rs  = rsqrtf(var + 1e-5f);
    const float4 wv = ((const float4*)lw)[t];
    const float4 bv = ((const float4*)lb)[t];
    u16x4 o;
    o.x = f2bf((xv.x - mu) * rs * wv.x + bv.x);
    o.y = f2bf((xv.y - mu) * rs * wv.y + bv.y);
    o.z = f2bf((xv.z - mu) * rs * wv.z + bv.z);
    o.w = f2bf((xv.w - mu) * rs * wv.w + bv.w);
    ((u16x4*)(xn + (size_t)row * 1024))[t] = o;
}

// ---------------------------------------------------------------------------
// Transpose + cast weights: w[1024][1024] fp32 -> wt[1024][1024] bf16 (wt[h][d])
// ---------------------------------------------------------------------------
__global__ void k_wt(const float* __restrict__ wq, const float* __restrict__ wk,
                     const float* __restrict__ wv, uint16_t* __restrict__ wt)
{
    __shared__ float tile[32][33];
    const int z = blockIdx.z;
    const float* W = (z == 0) ? wq : ((z == 1) ? wk : wv);
    uint16_t* T = wt + (size_t)z * 1024 * 1024;
    const int c0 = blockIdx.x * 32, r0 = blockIdx.y * 32;
    const int tx = threadIdx.x, ty = threadIdx.y;  // (32,8)
#pragma unroll
    for (int i = 0; i < 4; i++)
        tile[ty + 8 * i][tx] = W[(size_t)(r0 + ty + 8 * i) * 1024 + c0 + tx];
    __syncthreads();
#pragma unroll
    for (int i = 0; i < 4; i++)
        T[(size_t)(c0 + ty + 8 * i) * 1024 + r0 + tx] = f2bf(tile[tx][ty + 8 * i]);
}

// ---------------------------------------------------------------------------
// Transpose v bf16 [2048][1024] -> vt [1024][2048] per batch.
// ---------------------------------------------------------------------------
__global__ __launch_bounds__(256) void k_vt(
    const uint16_t* __restrict__ v, uint16_t* __restrict__ vt)
{
    __shared__ uint16_t tile[64][68];
    const int b = blockIdx.z;
    const uint16_t* V = v + (size_t)b * 2048 * 1024;
    uint16_t* T = vt + (size_t)b * 1024 * 2048;
    const int h0 = blockIdx.x * 64, t0 = blockIdx.y * 64;
    const int t = threadIdx.x;
    const int rr = t >> 4;
    const int cc = (t & 15) * 4;
#pragma unroll
    for (int i = 0; i < 4; i++) {
        const int tok = rr + 16 * i;
        *(u16x4*)&tile[tok][cc] =
            *(const u16x4*)&V[(size_t)(t0 + tok) * 1024 + h0 + cc];
    }
    __syncthreads();
#pragma unroll
    for (int i = 0; i < 4; i++) {
        const int h = rr + 16 * i;
        u16x4 o;
        o.x = tile[cc + 0][h];
        o.y = tile[cc + 1][h];
        o.z = tile[cc + 2][h];
        o.w = tile[cc + 3][h];
        *(u16x4*)&T[(size_t)(h0 + h) * 2048 + t0 + cc] = o;
    }
}

// ---------------------------------------------------------------------------
// Row softmax over S[8192][2048] fp32 (in place) + bf16 copy for the PV GEMM
// ---------------------------------------------------------------------------
__global__ __launch_bounds__(256) void k_softmax(
    float* __restrict__ S, uint16_t* __restrict__ attb)
{
    const size_t row = blockIdx.x;
    float* p = S + row * 2048;
    const int t = threadIdx.x;
    float4 a = ((float4*)p)[2 * t];
    float4 b = ((float4*)p)[2 * t + 1];
    float m = fmaxf(fmaxf(fmaxf(a.x, a.y), fmaxf(a.z, a.w)),
                    fmaxf(fmaxf(b.x, b.y), fmaxf(b.z, b.w)));
#pragma unroll
    for (int off = 32; off > 0; off >>= 1) m = fmaxf(m, __shfl_xor(m, off));
    __shared__ float pm[4], pl[4];
    const int w = t >> 6, lane = t & 63;
    if (lane == 0) pm[w] = m;
    __syncthreads();
    m = fmaxf(fmaxf(pm[0], pm[1]), fmaxf(pm[2], pm[3]));

    a.x = __expf(a.x - m); a.y = __expf(a.y - m);
    a.z = __expf(a.z - m); a.w = __expf(a.w - m);
    b.x = __expf(b.x - m); b.y = __expf(b.y - m);
    b.z = __expf(b.z - m); b.w = __expf(b.w - m);
    float s = a.x + a.y + a.z + a.w + b.x + b.y + b.z + b.w;
#pragma unroll
    for (int off = 32; off > 0; off >>= 1) s += __shfl_xor(s, off);
    if (lane == 0) pl[w] = s;
    __syncthreads();
    s = pl[0] + pl[1] + pl[2] + pl[3];
    const float inv = 1.f / s;

    a.x *= inv; a.y *= inv; a.z *= inv; a.w *= inv;
    b.x *= inv; b.y *= inv; b.z *= inv; b.w *= inv;
    ((float4*)p)[2 * t]     = a;
    ((float4*)p)[2 * t + 1] = b;

    uint16_t* q = attb + row * 2048 + t * 8;
    u16x4 o0, o1;
    o0.x = f2bf(a.x); o0.y = f2bf(a.y); o0.z = f2bf(a.z); o0.w = f2bf(a.w);
    o1.x = f2bf(b.x); o1.y = f2bf(b.y); o1.z = f2bf(b.z); o1.w = f2bf(b.w);
    ((u16x4*)q)[0] = o0;
    ((u16x4*)q)[1] = o1;
}

// ---------------------------------------------------------------------------
extern "C" void kernel_launch(void* const* d_in, const int* in_sizes, int n_in,
                              void* d_out, int out_size, void* d_ws, size_t ws_size,
                              hipStream_t stream)
{
    const float* x  = (const float*)d_in[0];
    const float* wq = (const float*)d_in[1];
    const float* bq = (const float*)d_in[2];
    const float* wk = (const float*)d_in[3];
    const float* bk = (const float*)d_in[4];
    const float* wv = (const float*)d_in[5];
    const float* bv = (const float*)d_in[6];
    const float* lw = (const float*)d_in[7];
    const float* lb = (const float*)d_in[8];

    float* att = (float*)d_out;                         // [4][2048][2048] = 64 MB
    float* out = (float*)d_out + (size_t)16777216;      // [4][2048][1024] = 32 MB

    // Scratch inside d_out's att region (dead until k_scores writes all of it):
    uint16_t* xn = (uint16_t*)d_out;                    // 8,388,608 elems (16.8 MB)
    uint16_t* wt = (uint16_t*)d_out + (size_t)8388608;  // 3,145,728 elems (6.3 MB)

    // ws layout (uint16 elems), exactly q+k+v = 25,165,824 elems = 50,331,648 B:
    uint16_t* ws   = (uint16_t*)d_ws;
    uint16_t* q    = ws;
    uint16_t* k    = ws + (size_t)8388608;
    uint16_t* v    = ws + (size_t)2 * 8388608;
    uint16_t* vt   = ws;                                // overlays dead q
    uint16_t* attb = ws + (size_t)8388608;              // overlays dead k+v
    uint16_t* qkv  = q;

    if (ws_size < (size_t)50331648) return;  // OOB guard: fail clean, not crash

    k_ln<<<8192, 256, 0, stream>>>(x, lw, lb, xn);
    k_wt<<<dim3(32, 32, 3), dim3(32, 8), 0, stream>>>(wq, wk, wv, wt);
    k_qkv<<<dim3(16, 32), 512, 0, stream>>>(xn, wt, bq, bk, bv, qkv);
    k_scores<<<dim3(8, 8, 4), 512, 0, stream>>>(q, k, att);     // frees q,k
    k_vt<<<dim3(16, 32, 4), 256, 0, stream>>>(v, vt);           // vt over dead q
    k_softmax<<<8192, 256, 0, stream>>>(att, attb);             // attb over dead k+v
    k_out<<<dim3(8, 8, 4), 512, 0, stream>>>(attb, vt, out);
}

// Round 4
// 306.671 us; speedup vs baseline: 1.1002x; 1.0021x over previous
//
#include <hip/hip_runtime.h>
#include <stdint.h>

// ---------------------------------------------------------------------------
// SelfAttention: LN -> QKV (bf16 MFMA GEMM) -> S=QK^T/32 -> softmax -> att*V
// B=4, N=2048, D=H=1024. Outputs: att fp32 [4,2048,2048] ++ out fp32 [4,2048,1024]
// R8: K-half software pipeline. R7 showed LDS-read and MFMA pipes ALTERNATE
//   (tile = reads+MFMA summed ~5300cy) because the first MFMA depended on read
//   20/22 of its own burst. Now each K-tile runs:
//     issue ks1 reads -> MFMA ks0 (operands prefetched last half)
//     -> lgkm0 [;bar;STGALL] ; vmw<OPS>; bar
//     -> issue ks0 reads of te+1 (other buffer) -> MFMA ks1
//   Every read batch has a trailing MFMA batch in-body; every MFMA's operands
//   were issued one half-tile earlier. Sync/vmcnt/rotation proven in R6/R7.
//   k_scores: BN=256 -> BN=128 (3-buf, 512 blocks = 2 uniform rounds).
// ---------------------------------------------------------------------------

typedef __attribute__((ext_vector_type(8))) short short8;   // 8 bf16 (4 VGPRs)
typedef __attribute__((ext_vector_type(4))) float floatx4;  // MFMA acc
typedef __attribute__((ext_vector_type(4))) uint16_t u16x4;

__device__ __forceinline__ uint16_t f2bf(float f) {
    union { float f; uint32_t u; } v; v.f = f;
    uint32_t r = v.u + 0x7fffu + ((v.u >> 16) & 1u);  // RNE
    return (uint16_t)(r >> 16);
}

// async global->LDS, 16B per lane. LDS dest is wave-uniform base + lane*16.
typedef const uint32_t __attribute__((address_space(1)))* gas1_t;
typedef uint32_t __attribute__((address_space(3)))* las3_t;
__device__ __forceinline__ void gload_lds16(const uint16_t* g, uint16_t* l) {
    __builtin_amdgcn_global_load_lds((gas1_t)g, (las3_t)l, 16, 0, 0);
}

__device__ __forceinline__ void s_bar()  { asm volatile("s_barrier" ::: "memory"); }
__device__ __forceinline__ void lgkm0()  { asm volatile("s_waitcnt lgkmcnt(0)" ::: "memory"); }
template<int N> __device__ __forceinline__ void vmw() {
    asm volatile("s_waitcnt vmcnt(%0)" :: "n"(N) : "memory");
}

// ---------------------------------------------------------------------------
// gemm_core<BN,EPI>: C = A * Bt^T. A:[M,K] bf16 rm, Bt:[N,K] bf16 rm. BM=256.
// 512 thr = 8 waves. BN=192: 2Mx4N waves (per-wave 128x48), 2-buf LDS.
// BN=128: 4Mx2N waves (per-wave 64x64), 3-buf LDS, 1 barrier/tile.
// BK=64 split into two K-halves ks0/ks1 (ksg0/ksg1 swizzled segs).
// 16B-seg XOR swizzle (phys_seg = seg ^ (row&7)) via pre-swizzled global src +
// linear LDS dest; readers XOR the same -> 0 bank conflicts (proven R4-R7).
// Hazards per tile: WAR = lgkm0 (+bar for 2-buf) before re-staging a read
// buffer; RAW = counted vmw<OPS> + bar before reading next tile's buffer.
// EPI 0: fp32 store * alpha.  EPI 1: fused-qkv bf16 + bias, 3072-wide cols
//        de-interleave into q|k|v planes of 8192x1024.
// ---------------------------------------------------------------------------

#define READS(BASE, KS)                                                   \
    { const uint16_t* LBp = (BASE) + ABUF;                                \
      _Pragma("unroll") for (int mi = 0; mi < MIW; ++mi)                  \
          Af[mi][KS] = *(const short8*)((BASE) + aoff + mi * 1024 +       \
                                        ((KS) ? ksg1 : ksg0));            \
      _Pragma("unroll") for (int ni = 0; ni < NIW; ++ni)                  \
          Bf[ni][KS] = *(const short8*)(LBp + boff + ni * 1024 +          \
                                        ((KS) ? ksg1 : ksg0)); }

#define MFMAS(KS)                                                         \
    __builtin_amdgcn_s_setprio(1);                                        \
    _Pragma("unroll") for (int mi = 0; mi < MIW; ++mi)                    \
    _Pragma("unroll") for (int ni = 0; ni < NIW; ++ni)                    \
        acc[mi][ni] = __builtin_amdgcn_mfma_f32_16x16x32_bf16(            \
            Af[mi][KS], Bf[ni][KS], acc[mi][ni], 0, 0, 0);                \
    __builtin_amdgcn_s_setprio(0);

template<int BN, int EPI>
__device__ __forceinline__ void gemm_core(
    const uint16_t* __restrict__ A, const uint16_t* __restrict__ Bt,
    const int K, const int NT, const int m0, const int n0,
    float* __restrict__ Cf, uint16_t* __restrict__ Cb, const int ldc,
    const float* __restrict__ bq, const float* __restrict__ bk,
    const float* __restrict__ bv, const float alpha)
{
    constexpr int ABUF  = 256 * 64;            // 16384 elems
    constexpr int BP    = BN / 64;             // B stage passes (3,2)
    constexpr int BBUF  = BN * 64;
    constexpr int BUFSZ = ABUF + BBUF;
    constexpr int OPS   = 4 + BP;              // stage ops per K-tile
    constexpr int NBUF  = (BN == 128) ? 3 : 2;
    constexpr int WAVES_N = (BN == 128) ? 2 : 4;
    constexpr int MIW  = (BN == 128) ? 4 : 8;  // mi frags per wave
    constexpr int NIW  = BN / (16 * WAVES_N);  // ni frags (4 or 3)
    __shared__ uint16_t sm[NBUF * BUFSZ + 4096];
    uint16_t* const trash = sm + NBUF * BUFSZ;

    const int t = threadIdx.x;

    // ---- staging geometry ----
    const int srow = t >> 3;                  // 0..63
    const int sseg = (t & 7) ^ (srow & 7);    // pre-swizzled global 16B-seg
    const uint16_t* gA = A + (size_t)(m0 + srow) * K + sseg * 8;
    const uint16_t* gB = Bt + (size_t)(n0 + srow) * K + sseg * 8;

    // stage one whole K-tile (OPS async gloads); kt>=NT -> trash (never read)
    auto STGALL = [&](int kt, int bi) {
        const int live = kt < NT;
        const size_t ko = (size_t)(live ? kt : 0) * 64;
        uint16_t* const db = sm + bi * BUFSZ + t * 8;
        uint16_t* const tr = trash + t * 8;
#pragma unroll
        for (int p = 0; p < 4; ++p)
            gload_lds16(gA + (size_t)(p * 64) * K + ko,
                        live ? (db + p * 4096) : tr);
#pragma unroll
        for (int p = 0; p < BP; ++p)
            gload_lds16(gB + (size_t)(p * 64) * K + ko,
                        live ? (db + ABUF + p * 4096) : tr);
    };

    // ---- reader geometry ----
    const int lane = t & 63;
    const int wid  = t >> 6;
    const int wm   = wid / WAVES_N;
    const int wn   = wid % WAVES_N;
    const int quad = lane >> 4;
    const int lrow = lane & 15;
    const int swz  = lrow & 7;
    const int ksg0 = (quad ^ swz) * 8;
    const int ksg1 = ((4 + quad) ^ swz) * 8;
    const int aoff = (wm * (16 * MIW) + lrow) * 64;
    const int boff = (wn * (16 * NIW) + lrow) * 64;

    floatx4 acc[MIW][NIW];
#pragma unroll
    for (int mi = 0; mi < MIW; ++mi)
#pragma unroll
        for (int ni = 0; ni < NIW; ++ni)
            acc[mi][ni] = floatx4{0.f, 0.f, 0.f, 0.f};

    short8 Af[MIW][2];
    short8 Bf[NIW][2];

    // ---- prologue: tiles 0,1 staged; wait tile0; prefetch its ks0 frags ----
    STGALL(0, 0);
    STGALL(1, 1);
    vmw<OPS>();
    s_bar();
    READS(sm, 0);

    int bcur = 0, bstage = 2;  // BN==128 3-buffer rotation only
    for (int te = 0; te < NT; ++te) {
        const uint16_t* LA;
        const uint16_t* LAn;
        if constexpr (BN == 128) {
            LA = sm + bcur * BUFSZ;
            const int bnext = (bcur == 2) ? 0 : bcur + 1;
            LAn = sm + bnext * BUFSZ;
            STGALL(te + 2, bstage);            // free buffer: no WAR wait
        } else {
            LA  = sm + (te & 1) * BUFSZ;
            LAn = sm + ((te + 1) & 1) * BUFSZ;
        }

        READS(LA, 1);                          // ks1 frags of te (issue only)
        MFMAS(0);                              // ks0: operands prefetched
        lgkm0();                               // own reads of LA complete (WAR)
        if constexpr (BN != 128) {
            s_bar();                           // all waves done reading bi
            STGALL(te + 2, te & 1);            // re-stage current buffer
        }
        vmw<OPS>();                            // te+1's stages landed (RAW)
        s_bar();
        READS(LAn, 0);                         // ks0 frags of te+1 (issue only)
        MFMAS(1);                              // ks1 of te; covers the reads

        if constexpr (BN == 128) {
            bcur   = (bcur == 2) ? 0 : bcur + 1;
            bstage = (bstage == 2) ? 0 : bstage + 1;
        }
    }

    vmw<0>();  // drain clamped trash stages

    // ---- epilogue: C/D layout col=lane&15, row=quad*4+reg [m89/m91] ----
    const int rbase = m0 + wm * (16 * MIW) + quad * 4;
    const int cbase = n0 + wn * (16 * NIW) + lrow;

    if constexpr (EPI == 1) {
        float bc[NIW];
#pragma unroll
        for (int ni = 0; ni < NIW; ++ni) {
            const int col = cbase + ni * 16;
            const int z = col >> 10;
            const float* bp = (z == 0) ? bq : ((z == 1) ? bk : bv);
            bc[ni] = bp[col & 1023];
        }
#pragma unroll
        for (int mi = 0; mi < MIW; ++mi) {
#pragma unroll
            for (int ni = 0; ni < NIW; ++ni) {
                const int row = rbase + mi * 16;
                const int col = cbase + ni * 16;
                const int z = col >> 10, h = col & 1023;
#pragma unroll
                for (int r = 0; r < 4; ++r)
                    Cb[(size_t)z * 8388608 + (size_t)(row + r) * 1024 + h] =
                        f2bf(acc[mi][ni][r] + bc[ni]);
            }
        }
    } else {
#pragma unroll
        for (int mi = 0; mi < MIW; ++mi) {
#pragma unroll
            for (int ni = 0; ni < NIW; ++ni) {
                const int row = rbase + mi * 16;
                const int col = cbase + ni * 16;
#pragma unroll
                for (int r = 0; r < 4; ++r)
                    Cf[(size_t)(row + r) * ldc + col] = acc[mi][ni][r] * alpha;
            }
        }
    }
}

// q|k|v = xn @ [wq|wk|wv]^T + bias, one GEMM M=8192 N=3072 K=1024, BN=192.
__global__ __launch_bounds__(512, 2) void k_qkv(
    const uint16_t* __restrict__ xn, const uint16_t* __restrict__ wt,
    const float* __restrict__ bq, const float* __restrict__ bk,
    const float* __restrict__ bv, uint16_t* __restrict__ qkv)
{
    // grid (16, 32) = 512 blocks -> 2 uniform rounds; bijective XCD swizzle
    const int flat = blockIdx.y * 16 + blockIdx.x;
    const int s = (flat & 7) * 64 + (flat >> 3);
    const int bx = s & 15, by = s >> 4;
    gemm_core<192, 1>(xn, wt, 1024, 16, by * 256, bx * 192,
                      nullptr, qkv, 0, bq, bk, bv, 0.f);
}

// S = q @ k^T * (1/32), fp32 into d_out att region. BN=128, 512 blocks.
__global__ __launch_bounds__(512, 2) void k_scores(
    const uint16_t* __restrict__ q, const uint16_t* __restrict__ k,
    float* __restrict__ S)
{
    const int flat = (blockIdx.z * 8 + blockIdx.y) * 16 + blockIdx.x;
    const int s = (flat & 7) * 64 + (flat >> 3);        // 512-bijective
    const int x = s & 15, y = (s >> 4) & 7, z = s >> 7;
    gemm_core<128, 0>(q + (size_t)z * 2048 * 1024, k + (size_t)z * 2048 * 1024,
                      1024, 16, y * 256, x * 128,
                      S + (size_t)z * 2048 * 2048, nullptr, 2048,
                      nullptr, nullptr, nullptr, 0.03125f);
}

// out = att_bf16 @ vt^T, fp32. BN=128, K=2048, grid 256 = 1/CU, 3-buf LDS.
__global__ __launch_bounds__(512, 2) void k_out(
    const uint16_t* __restrict__ attb, const uint16_t* __restrict__ vt,
    float* __restrict__ out)
{
    const int flat = blockIdx.z * 64 + blockIdx.y * 8 + blockIdx.x;
    const int s = (flat & 7) * 32 + (flat >> 3);        // 256-bijective
    const int z = s >> 6, y = (s >> 3) & 7, x = s & 7;
    gemm_core<128, 0>(attb + (size_t)z * 2048 * 2048, vt + (size_t)z * 1024 * 2048,
                      2048, 32, y * 256, x * 128,
                      out + (size_t)z * 2048 * 1024, nullptr, 1024,
                      nullptr, nullptr, nullptr, 1.0f);
}

// ---------------------------------------------------------------------------
// LayerNorm rows of x[8192][1024] -> bf16 xn
// ---------------------------------------------------------------------------
__global__ __launch_bounds__(256) void k_ln(
    const float* __restrict__ x, const float* __restrict__ lw,
    const float* __restrict__ lb, uint16_t* __restrict__ xn)
{
    const int row = blockIdx.x;
    const int t = threadIdx.x;
    const float* xr = x + (size_t)row * 1024;
    const float4 xv = ((const float4*)xr)[t];
    float s  = xv.x + xv.y + xv.z + xv.w;
    float s2 = xv.x * xv.x + xv.y * xv.y + xv.z * xv.z + xv.w * xv.w;
#pragma unroll
    for (int off = 32; off > 0; off >>= 1) {
        s  += __shfl_xor(s, off);
        s2 += __shfl_xor(s2, off);
    }
    __shared__ float ps[4], ps2[4];
    const int w = t >> 6, lane = t & 63;
    if (lane == 0) { ps[w] = s; ps2[w] = s2; }
    __syncthreads();
    s  = ps[0] + ps[1] + ps[2] + ps[3];
    s2 = ps2[0] + ps2[1] + ps2[2] + ps2[3];
    const float mu  = s * (1.f / 1024.f);
    const float var = s2 * (1.f / 1024.f) - mu * mu;
    const float rs  = rsqrtf(var + 1e-5f);
    const float4 wv = ((const float4*)lw)[t];
    const float4 bv = ((const float4*)lb)[t];
    u16x4 o;
    o.x = f2bf((xv.x - mu) * rs * wv.x + bv.x);
    o.y = f2bf((xv.y - mu) * rs * wv.y + bv.y);
    o.z = f2bf((xv.z - mu) * rs * wv.z + bv.z);
    o.w = f2bf((xv.w - mu) * rs * wv.w + bv.w);
    ((u16x4*)(xn + (size_t)row * 1024))[t] = o;
}

// ---------------------------------------------------------------------------
// Transpose + cast weights: w[1024][1024] fp32 -> wt[1024][1024] bf16 (wt[h][d])
// ---------------------------------------------------------------------------
__global__ void k_wt(const float* __restrict__ wq, const float* __restrict__ wk,
                     const float* __restrict__ wv, uint16_t* __restrict__ wt)
{
    __shared__ float tile[32][33];
    const int z = blockIdx.z;
    const float* W = (z == 0) ? wq : ((z == 1) ? wk : wv);
    uint16_t* T = wt + (size_t)z * 1024 * 1024;
    const int c0 = blockIdx.x * 32, r0 = blockIdx.y * 32;
    const int tx = threadIdx.x, ty = threadIdx.y;  // (32,8)
#pragma unroll
    for (int i = 0; i < 4; i++)
        tile[ty + 8 * i][tx] = W[(size_t)(r0 + ty + 8 * i) * 1024 + c0 + tx];
    __syncthreads();
#pragma unroll
    for (int i = 0; i < 4; i++)
        T[(size_t)(c0 + ty + 8 * i) * 1024 + r0 + tx] = f2bf(tile[tx][ty + 8 * i]);
}

// ---------------------------------------------------------------------------
// Transpose v bf16 [2048][1024] -> vt [1024][2048] per batch.
// ---------------------------------------------------------------------------
__global__ __launch_bounds__(256) void k_vt(
    const uint16_t* __restrict__ v, uint16_t* __restrict__ vt)
{
    __shared__ uint16_t tile[64][68];
    const int b = blockIdx.z;
    const uint16_t* V = v + (size_t)b * 2048 * 1024;
    uint16_t* T = vt + (size_t)b * 1024 * 2048;
    const int h0 = blockIdx.x * 64, t0 = blockIdx.y * 64;
    const int t = threadIdx.x;
    const int rr = t >> 4;
    const int cc = (t & 15) * 4;
#pragma unroll
    for (int i = 0; i < 4; i++) {
        const int tok = rr + 16 * i;
        *(u16x4*)&tile[tok][cc] =
            *(const u16x4*)&V[(size_t)(t0 + tok) * 1024 + h0 + cc];
    }
    __syncthreads();
#pragma unroll
    for (int i = 0; i < 4; i++) {
        const int h = rr + 16 * i;
        u16x4 o;
        o.x = tile[cc + 0][h];
        o.y = tile[cc + 1][h];
        o.z = tile[cc + 2][h];
        o.w = tile[cc + 3][h];
        *(u16x4*)&T[(size_t)(h0 + h) * 2048 + t0 + cc] = o;
    }
}

// ---------------------------------------------------------------------------
// Row softmax over S[8192][2048] fp32 (in place) + bf16 copy for the PV GEMM
// ---------------------------------------------------------------------------
__global__ __launch_bounds__(256) void k_softmax(
    float* __restrict__ S, uint16_t* __restrict__ attb)
{
    const size_t row = blockIdx.x;
    float* p = S + row * 2048;
    const int t = threadIdx.x;
    float4 a = ((float4*)p)[2 * t];
    float4 b = ((float4*)p)[2 * t + 1];
    float m = fmaxf(fmaxf(fmaxf(a.x, a.y), fmaxf(a.z, a.w)),
                    fmaxf(fmaxf(b.x, b.y), fmaxf(b.z, b.w)));
#pragma unroll
    for (int off = 32; off > 0; off >>= 1) m = fmaxf(m, __shfl_xor(m, off));
    __shared__ float pm[4], pl[4];
    const int w = t >> 6, lane = t & 63;
    if (lane == 0) pm[w] = m;
    __syncthreads();
    m = fmaxf(fmaxf(pm[0], pm[1]), fmaxf(pm[2], pm[3]));

    a.x = __expf(a.x - m); a.y = __expf(a.y - m);
    a.z = __expf(a.z - m); a.w = __expf(a.w - m);
    b.x = __expf(b.x - m); b.y = __expf(b.y - m);
    b.z = __expf(b.z - m); b.w = __expf(b.w - m);
    float s = a.x + a.y + a.z + a.w + b.x + b.y + b.z + b.w;
#pragma unroll
    for (int off = 32; off > 0; off >>= 1) s += __shfl_xor(s, off);
    if (lane == 0) pl[w] = s;
    __syncthreads();
    s = pl[0] + pl[1] + pl[2] + pl[3];
    const float inv = 1.f / s;

    a.x *= inv; a.y *= inv; a.z *= inv; a.w *= inv;
    b.x *= inv; b.y *= inv; b.z *= inv; b.w *= inv;
    ((float4*)p)[2 * t]     = a;
    ((float4*)p)[2 * t + 1] = b;

    uint16_t* q = attb + row * 2048 + t * 8;
    u16x4 o0, o1;
    o0.x = f2bf(a.x); o0.y = f2bf(a.y); o0.z = f2bf(a.z); o0.w = f2bf(a.w);
    o1.x = f2bf(b.x); o1.y = f2bf(b.y); o1.z = f2bf(b.z); o1.w = f2bf(b.w);
    ((u16x4*)q)[0] = o0;
    ((u16x4*)q)[1] = o1;
}

// ---------------------------------------------------------------------------
extern "C" void kernel_launch(void* const* d_in, const int* in_sizes, int n_in,
                              void* d_out, int out_size, void* d_ws, size_t ws_size,
                              hipStream_t stream)
{
    const float* x  = (const float*)d_in[0];
    const float* wq = (const float*)d_in[1];
    const float* bq = (const float*)d_in[2];
    const float* wk = (const float*)d_in[3];
    const float* bk = (const float*)d_in[4];
    const float* wv = (const float*)d_in[5];
    const float* bv = (const float*)d_in[6];
    const float* lw = (const float*)d_in[7];
    const float* lb = (const float*)d_in[8];

    float* att = (float*)d_out;                         // [4][2048][2048] = 64 MB
    float* out = (float*)d_out + (size_t)16777216;      // [4][2048][1024] = 32 MB

    // Scratch inside d_out's att region (dead until k_scores writes all of it):
    uint16_t* xn = (uint16_t*)d_out;                    // 8,388,608 elems (16.8 MB)
    uint16_t* wt = (uint16_t*)d_out + (size_t)8388608;  // 3,145,728 elems (6.3 MB)

    // ws layout (uint16 elems), exactly q+k+v = 25,165,824 elems = 50,331,648 B:
    uint16_t* ws   = (uint16_t*)d_ws;
    uint16_t* q    = ws;
    uint16_t* k    = ws + (size_t)8388608;
    uint16_t* v    = ws + (size_t)2 * 8388608;
    uint16_t* vt   = ws;                                // overlays dead q
    uint16_t* attb = ws + (size_t)8388608;              // overlays dead k+v
    uint16_t* qkv  = q;

    if (ws_size < (size_t)50331648) return;  // OOB guard: fail clean, not crash

    k_ln<<<8192, 256, 0, stream>>>(x, lw, lb, xn);
    k_wt<<<dim3(32, 32, 3), dim3(32, 8), 0, stream>>>(wq, wk, wv, wt);
    k_qkv<<<dim3(16, 32), 512, 0, stream>>>(xn, wt, bq, bk, bv, qkv);
    k_scores<<<dim3(16, 8, 4), 512, 0, stream>>>(q, k, att);    // frees q,k
    k_vt<<<dim3(16, 32, 4), 256, 0, stream>>>(v, vt);           // vt over dead q
    k_softmax<<<8192, 256, 0, stream>>>(att, attb);             // attb over dead k+v
    k_out<<<dim3(8, 8, 4), 512, 0, stream>>>(attb, vt, out);
}